// Round 1
// baseline (1187.404 us; speedup 1.0000x reference)
//
#include <hip/hip_runtime.h>
#include <hip/hip_fp16.h>
#include <stdint.h>

// ---------------------------------------------------------------------------
// SeqAE: enc LSTM (3->200, T=800, B=256) -> maxpool(T) -> dec LSTM (200->3)
// Encoder: 1 WG per batch (256 WGs). Whh as f16 pairs resident in VGPRs
// (400 worker threads x 2 rows x 100 pairs). h broadcast via LDS (f16 pairs).
// Decoder: per-thread scalar recurrence with bitwise fixed-point early exit.
// ---------------------------------------------------------------------------

typedef _Float16 half2_t __attribute__((ext_vector_type(2)));

__device__ __forceinline__ float fdot2f(uint32_t hp, uint32_t wp, float acc) {
#if __has_builtin(__builtin_amdgcn_fdot2)
  return __builtin_amdgcn_fdot2(__builtin_bit_cast(half2_t, hp),
                                __builtin_bit_cast(half2_t, wp), acc, false);
#else
  half2_t a = __builtin_bit_cast(half2_t, hp);
  half2_t b = __builtin_bit_cast(half2_t, wp);
  return acc + (float)a[0] * (float)b[0] + (float)a[1] * (float)b[1];
#endif
}

__device__ __forceinline__ float hsig(float z) {
  return fminf(fmaxf(__builtin_fmaf(0.2f, z, 0.5f), 0.f), 1.f);
}

// tanh(x) = 1 - 2/(1+e^{2x});  e^{2x} = exp2(x * 2*log2(e))
__device__ __forceinline__ float tanh_fast(float v) {
  float e = __builtin_amdgcn_exp2f(v * 2.885390081777927f);
  return 1.f - 2.f * __builtin_amdgcn_rcpf(e + 1.f);
}

// --- pack Whh (800x200 f32, row-major) into f16 pairs, layout wpk[pair][row]
__global__ void prep_kernel(const float* __restrict__ whh,
                            uint32_t* __restrict__ wpk) {
  int idx = blockIdx.x * 256 + threadIdx.x;      // 100 pairs * 800 rows
  if (idx >= 80000) return;
  int p = idx / 800;
  int j = idx - p * 800;
  float a = whh[j * 200 + 2 * p];
  float b = whh[j * 200 + 2 * p + 1];
  __half2 v = __floats2half2_rn(a, b);
  wpk[idx] = __builtin_bit_cast(uint32_t, v);
}

// --- encoder: grid 256 (batch), 448 threads (400 workers own rows t, t+400)
__global__ __launch_bounds__(448, 1)
void enc_kernel(const float* __restrict__ x,       // (256,3,800)
                const float* __restrict__ wih,     // (800,3)
                const float* __restrict__ bih,     // (800)
                const float* __restrict__ bhh,     // (800)
                const uint32_t* __restrict__ wpk,  // (100,800) f16 pairs
                const float* __restrict__ dwih,    // (12,200)
                const float* __restrict__ dbih,    // (12)
                const float* __restrict__ dbhh,    // (12)
                float* __restrict__ pre12)         // (256,12)
{
  const int b = blockIdx.x;
  const int t = threadIdx.x;

  __shared__ float xs[3 * 800];
  __shared__ alignas(16) __half hh[200];   // h_{t-1} as f16, pair-readable
  __shared__ float gates[800];
  __shared__ float pooled[200];

  for (int i = t; i < 2400; i += 448) xs[i] = x[(size_t)b * 2400 + i];
  if (t < 200) hh[t] = __float2half(0.f);

  const bool worker = t < 400;
  uint32_t w1[100], w2[100];
  float bias1 = 0.f, bias2 = 0.f;
  float wiA0 = 0, wiA1 = 0, wiA2 = 0, wiB0 = 0, wiB1 = 0, wiB2 = 0;
  if (worker) {
    const int r1 = t, r2 = t + 400;
#pragma unroll
    for (int p = 0; p < 100; ++p) {
      w1[p] = wpk[p * 800 + r1];      // coalesced across threads
      w2[p] = wpk[p * 800 + r2];
    }
    bias1 = bih[r1] + bhh[r1];
    bias2 = bih[r2] + bhh[r2];
    wiA0 = wih[r1 * 3 + 0]; wiA1 = wih[r1 * 3 + 1]; wiA2 = wih[r1 * 3 + 2];
    wiB0 = wih[r2 * 3 + 0]; wiB1 = wih[r2 * 3 + 1]; wiB2 = wih[r2 * 3 + 2];
  }
  float c_state = 0.f;
  float maxh = -INFINITY;
  __syncthreads();

  for (int step = 0; step < 800; ++step) {
    if (worker) {
      float a0 = 0.f, a1 = 0.f, d0 = 0.f, d1 = 0.f;
      const uint4* H4 = (const uint4*)hh;
#pragma unroll
      for (int q = 0; q < 25; ++q) {
        uint4 Hv = H4[q];                     // broadcast read: 4 h-pairs
        a0 = fdot2f(Hv.x, w1[4 * q + 0], a0);
        d0 = fdot2f(Hv.x, w2[4 * q + 0], d0);
        a1 = fdot2f(Hv.y, w1[4 * q + 1], a1);
        d1 = fdot2f(Hv.y, w2[4 * q + 1], d1);
        a0 = fdot2f(Hv.z, w1[4 * q + 2], a0);
        d0 = fdot2f(Hv.z, w2[4 * q + 2], d0);
        a1 = fdot2f(Hv.w, w1[4 * q + 3], a1);
        d1 = fdot2f(Hv.w, w2[4 * q + 3], d1);
      }
      float x0 = xs[step], x1 = xs[800 + step], x2 = xs[1600 + step];
      float g1 = a0 + a1 + bias1;
      g1 = __builtin_fmaf(wiA0, x0, g1);
      g1 = __builtin_fmaf(wiA1, x1, g1);
      g1 = __builtin_fmaf(wiA2, x2, g1);
      float g2 = d0 + d1 + bias2;
      g2 = __builtin_fmaf(wiB0, x0, g2);
      g2 = __builtin_fmaf(wiB1, x1, g2);
      g2 = __builtin_fmaf(wiB2, x2, g2);
      gates[t] = g1;          // rows 0..399  (i, f)
      gates[t + 400] = g2;    // rows 400..799 (g, o)
    }
    __syncthreads();
    if (t < 200) {
      float gi = gates[t], gf = gates[t + 200], gg = gates[t + 400], go = gates[t + 600];
      float i_ = hsig(gi), f_ = hsig(gf), o_ = hsig(go);
      float g_ = tanh_fast(gg);
      c_state = f_ * c_state + i_ * g_;
      float h_ = o_ * tanh_fast(c_state);
      maxh = fmaxf(maxh, h_);
      hh[t] = __float2half(h_);
    }
    __syncthreads();
  }

  if (t < 200) pooled[t] = maxh;
  __syncthreads();
  // decoder input is constant over time: pre12 = pooled @ dec_Wih^T + biases
  if (t < 12) {
    float s = dbih[t] + dbhh[t];
    const float* wr = dwih + t * 200;
#pragma unroll 8
    for (int u = 0; u < 200; ++u) s = __builtin_fmaf(pooled[u], wr[u], s);
    pre12[b * 12 + t] = s;
  }
}

// --- decoder: 4 WGs x 64 threads, thread = batch. Fixed-point early exit.
__global__ __launch_bounds__(64, 1)
void dec_kernel(const float* __restrict__ pre12,
                const float* __restrict__ dwhh,   // (12,3)
                float* __restrict__ out)          // (256,3,800)
{
  const int lane = threadIdx.x;
  const int b = blockIdx.x * 64 + lane;

  float pre[12];
#pragma unroll
  for (int j = 0; j < 12; ++j) pre[j] = pre12[b * 12 + j];
  float W[36];
#pragma unroll
  for (int j = 0; j < 36; ++j) W[j] = dwhh[j];

  float h0 = 0, h1 = 0, h2 = 0, c0 = 0, c1 = 0, c2 = 0;
  int tc = 800;
  float* ob = out + (size_t)b * 2400;

  for (int step = 0; step < 800; ++step) {
    float g[12];
#pragma unroll
    for (int j = 0; j < 12; ++j) {
      float v = pre[j];
      v = __builtin_fmaf(W[j * 3 + 0], h0, v);
      v = __builtin_fmaf(W[j * 3 + 1], h1, v);
      v = __builtin_fmaf(W[j * 3 + 2], h2, v);
      g[j] = v;
    }
    // gate order i(0..2) f(3..5) g(6..8) o(9..11)
    float nc0 = hsig(g[3]) * c0 + hsig(g[0]) * tanh_fast(g[6]);
    float nc1 = hsig(g[4]) * c1 + hsig(g[1]) * tanh_fast(g[7]);
    float nc2 = hsig(g[5]) * c2 + hsig(g[2]) * tanh_fast(g[8]);
    float nh0 = hsig(g[9])  * tanh_fast(nc0);
    float nh1 = hsig(g[10]) * tanh_fast(nc1);
    float nh2 = hsig(g[11]) * tanh_fast(nc2);
    bool same = (nh0 == h0) && (nh1 == h1) && (nh2 == h2) &&
                (nc0 == c0) && (nc1 == c1) && (nc2 == c2);
    ob[step] = nh0; ob[800 + step] = nh1; ob[1600 + step] = nh2;
    h0 = nh0; h1 = nh1; h2 = nh2; c0 = nc0; c1 = nc1; c2 = nc2;
    if (same) { tc = step + 1; break; }   // exact fixed point: all later h identical
  }

  __shared__ int s_tc[64];
  __shared__ float s_h[64][3];
  s_tc[lane] = tc;
  s_h[lane][0] = h0; s_h[lane][1] = h1; s_h[lane][2] = h2;
  __syncthreads();
  // cooperative coalesced tail fill
  for (int i = 0; i < 64; ++i) {
    const int start = s_tc[i];
    if (start >= 800) continue;
    float v0 = s_h[i][0], v1 = s_h[i][1], v2 = s_h[i][2];
    float* op = out + (size_t)(blockIdx.x * 64 + i) * 2400;
    for (int tt = start + lane; tt < 800; tt += 64) {
      op[tt] = v0; op[800 + tt] = v1; op[1600 + tt] = v2;
    }
  }
}

extern "C" void kernel_launch(void* const* d_in, const int* in_sizes, int n_in,
                              void* d_out, int out_size, void* d_ws, size_t ws_size,
                              hipStream_t stream)
{
  const float* x    = (const float*)d_in[0];
  const float* wih  = (const float*)d_in[1];
  const float* whh  = (const float*)d_in[2];
  const float* bih  = (const float*)d_in[3];
  const float* bhh  = (const float*)d_in[4];
  const float* dwih = (const float*)d_in[5];
  const float* dwhh = (const float*)d_in[6];
  const float* dbih = (const float*)d_in[7];
  const float* dbhh = (const float*)d_in[8];
  float* out = (float*)d_out;

  uint32_t* wpk = (uint32_t*)d_ws;                       // 320000 B
  float* pre12  = (float*)((char*)d_ws + 320000);        // 12288 B

  hipLaunchKernelGGL(prep_kernel, dim3(313), dim3(256), 0, stream, whh, wpk);
  hipLaunchKernelGGL(enc_kernel, dim3(256), dim3(448), 0, stream,
                     x, wih, bih, bhh, wpk, dwih, dbih, dbhh, pre12);
  hipLaunchKernelGGL(dec_kernel, dim3(4), dim3(64), 0, stream, pre12, dwhh, out);
}